// Round 3
// baseline (129.806 us; speedup 1.0000x reference)
//
#include <hip/hip_runtime.h>
#include <hip/hip_bf16.h>
#include <cstdint>

// STFT as im2col GEMM:  C[b,c,t] = sum_n K[c,n] * xpad[b, t*HOP+n]
// Barrier-free K-loop: B = 64-frame signal window resident in LDS (staged once,
// XOR-swizzled); A fragments loaded global->VGPR (L2-resident DFT matrix).
// A rows pair-interleaved: A'[2f+ri] = kernel[ri*513+f] -> coalesced float2 epilogue.

#define HOP 256
#define NFFT 1024
#define FB 513
#define NT 1025
#define NBATCH 16
#define MCH 1026
#define MP2 1280         // padded channel count = 5*256
#define SIGLEN 262144
#define SIGP 263168      // reflect-padded length = SIGLEN + 1024
#define TW 64            // frames per block
#define WSAMP 17152      // (TW-1)*HOP + NFFT
#define WGRAN 1072       // WSAMP*2/16 ... (17152*2/16 = 2144)  [see below]
#undef WGRAN
#define WGRAN 2144

typedef __attribute__((ext_vector_type(8))) short short8;
typedef __attribute__((ext_vector_type(4))) float f32x4;
typedef unsigned int u32;

__device__ __forceinline__ unsigned short f2bf(float f) {
  u32 u = __float_as_uint(f);
  u = (u + 0x7FFFu + ((u >> 16) & 1u)) >> 16;   // RNE
  return (unsigned short)u;
}

// ---- prologue 1: DFT kernel f32[1026][1024] -> bf16[1280][1024], PAIR-INTERLEAVED:
//      A'[2f+ri][n] = kern[ri*513+f][n];  rows >= 1026 zero.
__global__ __launch_bounds__(256) void prep_A(const float* __restrict__ kern,
                                              unsigned short* __restrict__ A) {
  size_t i8 = ((size_t)blockIdx.x * 256 + threadIdx.x) * 8;
  int row = (int)(i8 >> 10);
  int col = (int)(i8 & 1023);
  short8 v = {0, 0, 0, 0, 0, 0, 0, 0};
  if (row < MCH) {
    int f = row >> 1, ri = row & 1;
    int src_row = ri * FB + f;
    const float* s = kern + ((size_t)src_row << 10) + col;
#pragma unroll
    for (int e = 0; e < 8; ++e) v[e] = (short)f2bf(s[e]);
  }
  *(short8*)(A + i8) = v;
}

// ---- prologue 2: reflect-pad signal f32[16][262144] -> bf16[16][263168]
__global__ __launch_bounds__(256) void prep_S(const float* __restrict__ sig,
                                              unsigned short* __restrict__ S) {
  size_t i8 = ((size_t)blockIdx.x * 256 + threadIdx.x) * 8;
  int b = (int)(i8 / SIGP);
  int i = (int)(i8 - (size_t)b * SIGP);
  const float* sb = sig + (size_t)b * SIGLEN;
  short8 v;
#pragma unroll
  for (int e = 0; e < 8; ++e) {
    int j = i + e - 512;
    j = (j < 0) ? -j : j;
    j = (j >= SIGLEN) ? (2 * SIGLEN - 2 - j) : j;
    v[e] = (short)f2bf(sb[j]);
  }
  *(short8*)(S + i8) = v;
}

// async 16B global->LDS. LDS dest is wave-uniform; HW adds lane*16.
__device__ __forceinline__ void async16(void* lds, const void* g) {
  __builtin_amdgcn_global_load_lds(
      (const __attribute__((address_space(1))) u32*)g,
      (__attribute__((address_space(3))) u32*)lds, 16, 0, 0);
}

// ---- main kernel ----
// 256 thr = 4 waves, each wave = 64M x 64T; block = 256M x 64T, one batch.
// LDS: flat signal window [17152] bf16, XOR-swizzle p = q ^ (((q>>9)&7)<<4)
// (bits 9-11 of byte addr -> bits 4-6; involution; granule-aligned).
// K-loop: A frags global->reg (imm-offset folded), B frags ds_read_b128, 0 barriers.
__global__ __launch_bounds__(256, 4) void stft_mm(const unsigned short* __restrict__ A,
                                                  const unsigned short* __restrict__ S,
                                                  float* __restrict__ out) {
  __shared__ __align__(16) short sW[WSAMP];

  const int tid = threadIdx.x;
  const int lane = tid & 63;
  const int wid = tid >> 6;
  const int lr = lane & 15;
  const int g16 = lane >> 4;

  // bijective XCD-chunk swizzle: nwg = 1360 = 8 * 170
  const int bid = blockIdx.x;
  const int wg = (bid & 7) * 170 + (bid >> 3);
  const int bm = wg % 5;
  const int r2 = wg / 5;
  const int bt = r2 % 17;
  const int b  = r2 / 17;

  const int c0 = bm * 256;
  const int t0 = bt * TW;

  const unsigned short* Sb = S + (size_t)b * SIGP;
  const size_t w0 = (size_t)t0 * HOP;

  // ---- stage signal window once: 2144 granules of 16B ----
#pragma unroll
  for (int i = 0; i < 9; ++i) {
    const int base = i * 256 + wid * 64;          // wave-uniform granule base
    if (base < WGRAN) {
      u32 p = (u32)(base + lane) * 16u;           // physical LDS byte
      u32 q = p ^ (((p >> 9) & 7u) << 4);         // logical byte (involution)
      size_t src = w0 + (size_t)(q >> 1);
      if (src > (size_t)(SIGP - 8)) src = SIGP - 8;   // clamp (masked at store)
      async16((char*)sW + (size_t)base * 16u, Sb + src);
    }
  }
  __syncthreads();

  // ---- per-lane bases ----
  const char* pA[4];
#pragma unroll
  for (int mi = 0; mi < 4; ++mi) {
    int row = c0 + wid * 64 + mi * 16 + lr;
    pA[mi] = (const char*)(A + ((size_t)row << 10)) + g16 * 16;
  }
  u32 bq[4];   // logical LDS byte base: tl*512 + g16*16
#pragma unroll
  for (int ni = 0; ni < 4; ++ni) bq[ni] = (u32)((ni * 16 + lr) * 512 + g16 * 16);

  f32x4 acc[4][4] = {};

#pragma unroll
  for (int kt = 0; kt < 16; ++kt) {
#pragma unroll
    for (int h = 0; h < 2; ++h) {
      const int koff = kt * 128 + h * 64;   // byte offset in both A row and window k
      short8 af[4], bfv[4];
#pragma unroll
      for (int mi = 0; mi < 4; ++mi)
        af[mi] = *(const short8*)(pA[mi] + koff);
#pragma unroll
      for (int ni = 0; ni < 4; ++ni) {
        u32 q = bq[ni] + (u32)koff;
        u32 p = q ^ (((q >> 9) & 7u) << 4);
        bfv[ni] = *(const short8*)((const char*)sW + p);
      }
#pragma unroll
      for (int mi = 0; mi < 4; ++mi)
#pragma unroll
        for (int ni = 0; ni < 4; ++ni)
          acc[mi][ni] =
              __builtin_amdgcn_mfma_f32_16x16x32_bf16(af[mi], bfv[ni], acc[mi][ni], 0, 0, 0);
    }
  }

  // ---- epilogue: D row (lane>>4)*4+r = c' (paired), col lane&15 = t ----
  // c' = 2f+ri -> float2 {ri=0,ri=1} at out[b][f][t][*]; fully coalesced.
#pragma unroll
  for (int mi = 0; mi < 4; ++mi) {
    const int cb = c0 + wid * 64 + mi * 16 + g16 * 4;   // even
    const int f0 = cb >> 1;
#pragma unroll
    for (int ni = 0; ni < 4; ++ni) {
      const int t = t0 + ni * 16 + lr;
      if (t < NT) {
        if (f0 < FB) {
          *(float2*)(out + ((((size_t)b * FB + f0) * NT + t) << 1)) =
              make_float2(acc[mi][ni][0], acc[mi][ni][1]);
        }
        if (f0 + 1 < FB) {
          *(float2*)(out + ((((size_t)b * FB + f0 + 1) * NT + t) << 1)) =
              make_float2(acc[mi][ni][2], acc[mi][ni][3]);
        }
      }
    }
  }
}

extern "C" void kernel_launch(void* const* d_in, const int* in_sizes, int n_in,
                              void* d_out, int out_size, void* d_ws, size_t ws_size,
                              hipStream_t stream) {
  const float* sig = (const float*)d_in[0];    // (16, 262144) f32
  const float* kern = (const float*)d_in[1];   // (1026, 1024) f32
  float* out = (float*)d_out;                  // (16, 513, 1025, 2) f32

  unsigned short* wsA = (unsigned short*)d_ws;               // 1280*1024 bf16
  unsigned short* wsS = wsA + (size_t)MP2 * NFFT;            // 16*263168 bf16
  // ws use: (1280*1024 + 16*263168)*2 = 11,042,816 bytes

  prep_A<<<dim3(MP2 * NFFT / 8 / 256), 256, 0, stream>>>(kern, wsA);
  prep_S<<<dim3(NBATCH * SIGP / 8 / 256), 256, 0, stream>>>(sig, wsS);
  stft_mm<<<dim3(5 * 17 * NBATCH), 256, 0, stream>>>(wsA, wsS, out);
}

// Round 4
// 116.773 us; speedup vs baseline: 1.1116x; 1.1116x over previous
//
#include <hip/hip_runtime.h>
#include <hip/hip_bf16.h>
#include <cstdint>

// STFT as im2col GEMM:  C[b,c,t] = sum_n K[c,n] * xpad[b, t*HOP+n]
// Barrier-free K-loop: B = 64-frame signal window resident in LDS (staged once,
// XOR-swizzled); A fragments loaded global->VGPR (L2-resident DFT matrix) with
// MANUAL prefetch-distance-1 double buffering (named regs, static indexing).
// A rows pair-interleaved: A'[2f+ri] = kernel[ri*513+f] -> coalesced float2 epilogue.

#define HOP 256
#define NFFT 1024
#define FB 513
#define NT 1025
#define NBATCH 16
#define MCH 1026
#define MP2 1280         // padded channel count = 5*256
#define SIGLEN 262144
#define SIGP 263168      // reflect-padded length = SIGLEN + 1024
#define TW 64            // frames per block
#define WSAMP 17152      // (TW-1)*HOP + NFFT
#define WGRAN 2144       // WSAMP*2/16 granules of 16B

typedef __attribute__((ext_vector_type(8))) short short8;
typedef __attribute__((ext_vector_type(4))) float f32x4;
typedef unsigned int u32;

__device__ __forceinline__ unsigned short f2bf(float f) {
  u32 u = __float_as_uint(f);
  u = (u + 0x7FFFu + ((u >> 16) & 1u)) >> 16;   // RNE
  return (unsigned short)u;
}

// ---- prologue 1: DFT kernel f32[1026][1024] -> bf16[1280][1024], PAIR-INTERLEAVED:
//      A'[2f+ri][n] = kern[ri*513+f][n];  rows >= 1026 zero.
__global__ __launch_bounds__(256) void prep_A(const float* __restrict__ kern,
                                              unsigned short* __restrict__ A) {
  size_t i8 = ((size_t)blockIdx.x * 256 + threadIdx.x) * 8;
  int row = (int)(i8 >> 10);
  int col = (int)(i8 & 1023);
  short8 v = {0, 0, 0, 0, 0, 0, 0, 0};
  if (row < MCH) {
    int f = row >> 1, ri = row & 1;
    int src_row = ri * FB + f;
    const float* s = kern + ((size_t)src_row << 10) + col;
#pragma unroll
    for (int e = 0; e < 8; ++e) v[e] = (short)f2bf(s[e]);
  }
  *(short8*)(A + i8) = v;
}

// ---- prologue 2: reflect-pad signal f32[16][262144] -> bf16[16][263168]
__global__ __launch_bounds__(256) void prep_S(const float* __restrict__ sig,
                                              unsigned short* __restrict__ S) {
  size_t i8 = ((size_t)blockIdx.x * 256 + threadIdx.x) * 8;
  int b = (int)(i8 / SIGP);
  int i = (int)(i8 - (size_t)b * SIGP);
  const float* sb = sig + (size_t)b * SIGLEN;
  short8 v;
#pragma unroll
  for (int e = 0; e < 8; ++e) {
    int j = i + e - 512;
    j = (j < 0) ? -j : j;
    j = (j >= SIGLEN) ? (2 * SIGLEN - 2 - j) : j;
    v[e] = (short)f2bf(sb[j]);
  }
  *(short8*)(S + i8) = v;
}

// async 16B global->LDS. LDS dest is wave-uniform; HW adds lane*16.
__device__ __forceinline__ void async16(void* lds, const void* g) {
  __builtin_amdgcn_global_load_lds(
      (const __attribute__((address_space(1))) u32*)g,
      (__attribute__((address_space(3))) u32*)lds, 16, 0, 0);
}

// ---- main kernel ----
// 256 thr = 4 waves, each wave = 64M x 64T; block = 256M x 64T, one batch.
// LDS: flat signal window [17152] bf16, XOR-swizzle p = q ^ (((q>>9)&7)<<4).
// K-loop: A global->reg prefetch d=1 (named dbuf), B ds_read prefetch d=1, 0 barriers.
__global__ __launch_bounds__(256, 2) void stft_mm(const unsigned short* __restrict__ A,
                                                  const unsigned short* __restrict__ S,
                                                  float* __restrict__ out) {
  __shared__ __align__(16) short sW[WSAMP];

  const int tid = threadIdx.x;
  const int lane = tid & 63;
  const int wid = tid >> 6;
  const int lr = lane & 15;
  const int g16 = lane >> 4;

  // bijective XCD-chunk swizzle: nwg = 1360 = 8 * 170
  const int bid = blockIdx.x;
  const int wg = (bid & 7) * 170 + (bid >> 3);
  const int bm = wg % 5;
  const int r2 = wg / 5;
  const int bt = r2 % 17;
  const int b  = r2 / 17;

  const int c0 = bm * 256;
  const int t0 = bt * TW;

  const unsigned short* Sb = S + (size_t)b * SIGP;
  const size_t w0 = (size_t)t0 * HOP;

  // ---- stage signal window once: 2144 granules of 16B ----
#pragma unroll
  for (int i = 0; i < 9; ++i) {
    const int base = i * 256 + wid * 64;          // wave-uniform granule base
    if (base < WGRAN) {
      u32 p = (u32)(base + lane) * 16u;           // physical LDS byte
      u32 q = p ^ (((p >> 9) & 7u) << 4);         // logical byte (involution)
      size_t src = w0 + (size_t)(q >> 1);
      if (src > (size_t)(SIGP - 8)) src = SIGP - 8;   // clamp (masked at store)
      async16((char*)sW + (size_t)base * 16u, Sb + src);
    }
  }
  __syncthreads();

  // ---- per-lane bases ----
  const char* pA[4];
#pragma unroll
  for (int mi = 0; mi < 4; ++mi) {
    int row = c0 + wid * 64 + mi * 16 + lr;
    pA[mi] = (const char*)(A + ((size_t)row << 10)) + g16 * 16;
  }
  u32 bq[4];   // logical LDS byte base: tl*512 + g16*16
#pragma unroll
  for (int ni = 0; ni < 4; ++ni) bq[ni] = (u32)((ni * 16 + lr) * 512 + g16 * 16);

  f32x4 acc[4][4] = {};

  short8 afA[4], afB[4], bfA[4], bfB[4];

#define LOAD_A(dst, koff)                                         \
  _Pragma("unroll") for (int mi = 0; mi < 4; ++mi)                \
      dst[mi] = *(const short8*)(pA[mi] + (koff));

#define LOAD_B(dst, koff)                                         \
  _Pragma("unroll") for (int ni = 0; ni < 4; ++ni) {              \
    u32 q = bq[ni] + (u32)(koff);                                 \
    u32 p = q ^ (((q >> 9) & 7u) << 4);                           \
    dst[ni] = *(const short8*)((const char*)sW + p);              \
  }

#define DO_MFMA(af, bfv)                                          \
  _Pragma("unroll") for (int mi = 0; mi < 4; ++mi)                \
  _Pragma("unroll") for (int ni = 0; ni < 4; ++ni)                \
      acc[mi][ni] = __builtin_amdgcn_mfma_f32_16x16x32_bf16(      \
          af[mi], bfv[ni], acc[mi][ni], 0, 0, 0);

  LOAD_A(afA, 0)
  LOAD_B(bfA, 0)
#pragma unroll
  for (int s = 0; s < 32; s += 2) {
    // even step: consume A-bank, prefetch B-bank for s+1
    LOAD_A(afB, (s + 1) * 64)
    LOAD_B(bfB, (s + 1) * 64)
    DO_MFMA(afA, bfA)
    // odd step: consume B-bank, prefetch A-bank for s+2
    if (s + 2 < 32) {
      LOAD_A(afA, (s + 2) * 64)
      LOAD_B(bfA, (s + 2) * 64)
    }
    DO_MFMA(afB, bfB)
  }

  // ---- epilogue: D row (lane>>4)*4+r = c' (paired), col lane&15 = t ----
  // c' = 2f+ri -> float2 {ri=0,ri=1} at out[b][f][t][*]; fully coalesced.
#pragma unroll
  for (int mi = 0; mi < 4; ++mi) {
    const int cb = c0 + wid * 64 + mi * 16 + g16 * 4;   // even
    const int f0 = cb >> 1;
#pragma unroll
    for (int ni = 0; ni < 4; ++ni) {
      const int t = t0 + ni * 16 + lr;
      if (t < NT) {
        if (f0 < FB) {
          *(float2*)(out + ((((size_t)b * FB + f0) * NT + t) << 1)) =
              make_float2(acc[mi][ni][0], acc[mi][ni][1]);
        }
        if (f0 + 1 < FB) {
          *(float2*)(out + ((((size_t)b * FB + f0 + 1) * NT + t) << 1)) =
              make_float2(acc[mi][ni][2], acc[mi][ni][3]);
        }
      }
    }
  }
}

extern "C" void kernel_launch(void* const* d_in, const int* in_sizes, int n_in,
                              void* d_out, int out_size, void* d_ws, size_t ws_size,
                              hipStream_t stream) {
  const float* sig = (const float*)d_in[0];    // (16, 262144) f32
  const float* kern = (const float*)d_in[1];   // (1026, 1024) f32
  float* out = (float*)d_out;                  // (16, 513, 1025, 2) f32

  unsigned short* wsA = (unsigned short*)d_ws;               // 1280*1024 bf16
  unsigned short* wsS = wsA + (size_t)MP2 * NFFT;            // 16*263168 bf16
  // ws use: (1280*1024 + 16*263168)*2 = 11,042,816 bytes

  prep_A<<<dim3(MP2 * NFFT / 8 / 256), 256, 0, stream>>>(kern, wsA);
  prep_S<<<dim3(NBATCH * SIGP / 8 / 256), 256, 0, stream>>>(sig, wsS);
  stft_mm<<<dim3(5 * 17 * NBATCH), 256, 0, stream>>>(wsA, wsS, out);
}

// Round 6
// 64.966 us; speedup vs baseline: 1.9981x; 1.7975x over previous
//
#include <hip/hip_runtime.h>
#include <hip/hip_bf16.h>
#include <cstdint>

// STFT as im2col GEMM:  C[b,c,t] = sum_n K[c,n] * xpad[b, t*HOP+n]
// Main GEMM covers channels 0..1023 x frames 0..1023 (no masking); the Nyquist
// channel pair (rows 1024,1025) and the last frame (t=1024) go to stft_edge.
// K-loop: 3-slot LDS ring (A 32KB + B 16KB per slot), stage-2-ahead via
// global_load_lds, counted s_waitcnt vmcnt(6), ONE raw s_barrier per K-tile.

#define HOP 256
#define NFFT 1024
#define FB 513
#define NT 1025
#define NBATCH 16
#define MCH 1026
#define MP2 1280         // padded channel rows in workspace A
#define SIGLEN 262144
#define SIGP 263168      // reflect-padded length
#define BM 256
#define BN 128
#define BK 64
#define NKT 16           // K tiles (1024 / 64)
#define SLOT_BYTES 49152 // A tile 32KB + B tile 16KB
#define LDS_BYTES (3 * SLOT_BYTES)

typedef __attribute__((ext_vector_type(8))) short short8;
typedef __attribute__((ext_vector_type(4))) float f32x4;
typedef unsigned int u32;

__device__ __forceinline__ unsigned short f2bf(float f) {
  u32 u = __float_as_uint(f);
  u = (u + 0x7FFFu + ((u >> 16) & 1u)) >> 16;   // RNE
  return (unsigned short)u;
}
__device__ __forceinline__ float bf2f(unsigned short s) {
  return __uint_as_float(((u32)s) << 16);
}

// ---- prologue 1: DFT kernel f32[1026][1024] -> bf16[1280][1024], PAIR-INTERLEAVED:
//      A'[2f+ri][n] = kern[ri*513+f][n];  rows >= 1026 zero.
__global__ __launch_bounds__(256) void prep_A(const float* __restrict__ kern,
                                              unsigned short* __restrict__ A) {
  size_t i8 = ((size_t)blockIdx.x * 256 + threadIdx.x) * 8;
  int row = (int)(i8 >> 10);
  int col = (int)(i8 & 1023);
  short8 v = {0, 0, 0, 0, 0, 0, 0, 0};
  if (row < MCH) {
    int f = row >> 1, ri = row & 1;
    int src_row = ri * FB + f;
    const float* s = kern + ((size_t)src_row << 10) + col;
#pragma unroll
    for (int e = 0; e < 8; ++e) v[e] = (short)f2bf(s[e]);
  }
  *(short8*)(A + i8) = v;
}

// ---- prologue 2: reflect-pad signal f32[16][262144] -> bf16[16][263168]
__global__ __launch_bounds__(256) void prep_S(const float* __restrict__ sig,
                                              unsigned short* __restrict__ S) {
  size_t i8 = ((size_t)blockIdx.x * 256 + threadIdx.x) * 8;
  int b = (int)(i8 / SIGP);
  int i = (int)(i8 - (size_t)b * SIGP);
  const float* sb = sig + (size_t)b * SIGLEN;
  short8 v;
#pragma unroll
  for (int e = 0; e < 8; ++e) {
    int j = i + e - 512;
    j = (j < 0) ? -j : j;
    j = (j >= SIGLEN) ? (2 * SIGLEN - 2 - j) : j;
    v[e] = (short)f2bf(sb[j]);
  }
  *(short8*)(S + i8) = v;
}

// async 16B global->LDS. LDS dest is wave-uniform; HW adds lane*16.
__device__ __forceinline__ void async16(void* lds, const void* g) {
  __builtin_amdgcn_global_load_lds(
      (const __attribute__((address_space(1))) u32*)g,
      (__attribute__((address_space(3))) u32*)lds, 16, 0, 0);
}

// ---- main GEMM ----
// 512 thr = 8 waves (wr=wid>>1 in 0..3 over M, wc=wid&1 over N).
// Tiles [rows][128B] bf16 in LDS with XOR swizzle p = q ^ (((q>>7)&7)<<4)
// (R1-proven: 0 bank conflicts). Linear gload_lds dest + inverse-swizzled src.
__global__ __launch_bounds__(512, 2) void stft_mm(const unsigned short* __restrict__ A,
                                                  const unsigned short* __restrict__ S,
                                                  float* __restrict__ out) {
  extern __shared__ char smem[];

  const int tid = threadIdx.x;
  const int lane = tid & 63;
  const int wid = tid >> 6;
  const int wr = wid >> 1;   // 0..3  (M quarter)
  const int wc = wid & 1;    // 0..1  (N half)
  const int lr = lane & 15;
  const int g16 = lane >> 4;

  // bijective XCD-chunk swizzle: nwg = 512 = 8 * 64
  const int bid = blockIdx.x;
  const int wg = (bid & 7) * 64 + (bid >> 3);
  const int mt = wg & 3;
  const int r2 = wg >> 2;
  const int nt = r2 & 7;
  const int b  = r2 >> 3;

  const int c0 = mt * BM;    // 0..768 (+255 <= 1023: always valid)
  const int t0 = nt * BN;    // 0..896 (+127 <= 1023: always valid)

  const char* Ab = (const char*)A;
  const char* Sb = (const char*)(S + (size_t)b * SIGP);

  // Stage K-tile kt into ring slot s. A: 2048 granules (4/thread); B: 1024 (2/thread).
#define STAGE_TILE(kt, s)                                                      \
  {                                                                            \
    char* As_ = smem + (s) * SLOT_BYTES;                                       \
    char* Bs_ = As_ + 32768;                                                   \
    _Pragma("unroll") for (int j = 0; j < 4; ++j) {                            \
      const int G0 = j * 512 + wid * 64;                                       \
      u32 p = (u32)(G0 + lane) * 16u;                                          \
      u32 q = p ^ (((p >> 7) & 7u) << 4);                                      \
      const char* src = Ab + ((size_t)(c0 + (int)(q >> 7)) << 11)              \
                           + (kt) * 128 + (int)(q & 127u);                     \
      async16(As_ + (size_t)G0 * 16u, src);                                    \
    }                                                                          \
    _Pragma("unroll") for (int j = 0; j < 2; ++j) {                            \
      const int G0 = j * 512 + wid * 64;                                       \
      u32 p = (u32)(G0 + lane) * 16u;                                          \
      u32 q = p ^ (((p >> 7) & 7u) << 4);                                      \
      const char* src = Sb + ((size_t)(t0 + (int)(q >> 7)) << 9)               \
                           + (kt) * 128 + (int)(q & 127u);                     \
      async16(Bs_ + (size_t)G0 * 16u, src);                                    \
    }                                                                          \
  }

  // prologue: fill slots 0,1 (12 loads/thread); gate tile0 landed (leave tile1)
  STAGE_TILE(0, 0)
  STAGE_TILE(1, 1)
  asm volatile("s_waitcnt vmcnt(6)" ::: "memory");
  __builtin_amdgcn_s_barrier();
  asm volatile("" ::: "memory");

  // per-lane logical read offsets (within tile)
  u32 qa[4], qb[4];
#pragma unroll
  for (int mi = 0; mi < 4; ++mi) qa[mi] = (u32)((wr * 64 + mi * 16 + lr) * 128 + g16 * 16);
#pragma unroll
  for (int ni = 0; ni < 4; ++ni) qb[ni] = (u32)((wc * 64 + ni * 16 + lr) * 128 + g16 * 16);

  f32x4 acc[4][4] = {};

#pragma unroll
  for (int k = 0; k < NKT; ++k) {
    const char* As = smem + (k % 3) * SLOT_BYTES;
    const char* Bs = As + 32768;
    // ds-reads of tile k (valid: gated at end of k-1, visible via barrier)
    short8 af[2][4], bfv[2][4];
#pragma unroll
    for (int h = 0; h < 2; ++h) {
#pragma unroll
      for (int mi = 0; mi < 4; ++mi) {
        u32 q = qa[mi] + (u32)(h * 64);
        u32 p = q ^ (((q >> 7) & 7u) << 4);
        af[h][mi] = *(const short8*)(As + p);
      }
#pragma unroll
      for (int ni = 0; ni < 4; ++ni) {
        u32 q = qb[ni] + (u32)(h * 64);
        u32 p = q ^ (((q >> 7) & 7u) << 4);
        bfv[h][ni] = *(const short8*)(Bs + p);
      }
    }
    // stage tile k+2 into slot (k+2)%3 == (k-1)%3: its last reader finished
    // before barrier k-1  -> WAR-safe for every wave.
    if (k + 2 < NKT) STAGE_TILE(k + 2, (k + 2) % 3)
    // 32 MFMA while staging loads fly
#pragma unroll
    for (int h = 0; h < 2; ++h)
#pragma unroll
      for (int mi = 0; mi < 4; ++mi)
#pragma unroll
        for (int ni = 0; ni < 4; ++ni)
          acc[mi][ni] = __builtin_amdgcn_mfma_f32_16x16x32_bf16(
              af[h][mi], bfv[h][ni], acc[mi][ni], 0, 0, 0);
    // gate: tile k+1 landed (leave tile k+2's 6 loads in flight); then barrier
    if (k <= NKT - 3)      asm volatile("s_waitcnt vmcnt(6)" ::: "memory");
    else                   asm volatile("s_waitcnt vmcnt(0)" ::: "memory");
    __builtin_amdgcn_s_barrier();
    asm volatile("" ::: "memory");
  }
#undef STAGE_TILE

  // epilogue: D row (lane>>4)*4+r = c' (paired), col lane&15 = t. No masks needed.
#pragma unroll
  for (int mi = 0; mi < 4; ++mi) {
    const int cb = c0 + wr * 64 + mi * 16 + g16 * 4;   // even
    const int f0 = cb >> 1;                            // < 512
#pragma unroll
    for (int ni = 0; ni < 4; ++ni) {
      const int t = t0 + wc * 64 + ni * 16 + lr;       // < 1024
      *(float2*)(out + ((((size_t)b * FB + f0) * NT + t) << 1)) =
          make_float2(acc[mi][ni][0], acc[mi][ni][1]);
      *(float2*)(out + ((((size_t)b * FB + f0 + 1) * NT + t) << 1)) =
          make_float2(acc[mi][ni][2], acc[mi][ni][3]);
    }
  }
}

// ---- edge kernel: Nyquist rows (f=512, all t) and last frame (t=1024, all f) ----
// One wave per output pair (f, t): two 1024-length dots in fp32 from bf16 ws.
__global__ __launch_bounds__(256) void stft_edge(const unsigned short* __restrict__ A,
                                                 const unsigned short* __restrict__ S,
                                                 float* __restrict__ out) {
  const int wv = blockIdx.x * 4 + (threadIdx.x >> 6);
  const int lane = threadIdx.x & 63;
  int b, f, t;
  if (wv < NBATCH * NT) {          // slice a: f = 512, t = 0..1024
    b = wv / NT; t = wv - b * NT; f = FB - 1;
  } else {                          // slice b: t = 1024, f = 0..512
    int u = wv - NBATCH * NT;
    b = u / FB; f = u - b * FB; t = NT - 1;
  }
  const unsigned short* w  = S + (size_t)b * SIGP + (size_t)t * HOP + lane * 16;
  const unsigned short* r0 = A + ((size_t)(2 * f) << 10) + lane * 16;
  const unsigned short* r1 = r0 + 1024;
  short8 wv0 = *(const short8*)w,  wv1 = *(const short8*)(w + 8);
  short8 a0  = *(const short8*)r0, a1  = *(const short8*)(r0 + 8);
  short8 b0  = *(const short8*)r1, b1  = *(const short8*)(r1 + 8);
  float d0 = 0.f, d1 = 0.f;
#pragma unroll
  for (int e = 0; e < 8; ++e) {
    float x0 = bf2f((unsigned short)wv0[e]), x1 = bf2f((unsigned short)wv1[e]);
    d0 += bf2f((unsigned short)a0[e]) * x0 + bf2f((unsigned short)a1[e]) * x1;
    d1 += bf2f((unsigned short)b0[e]) * x0 + bf2f((unsigned short)b1[e]) * x1;
  }
#pragma unroll
  for (int m = 32; m; m >>= 1) {
    d0 += __shfl_xor(d0, m);
    d1 += __shfl_xor(d1, m);
  }
  if (lane == 0)
    *(float2*)(out + ((((size_t)b * FB + f) * NT + t) << 1)) = make_float2(d0, d1);
}

extern "C" void kernel_launch(void* const* d_in, const int* in_sizes, int n_in,
                              void* d_out, int out_size, void* d_ws, size_t ws_size,
                              hipStream_t stream) {
  const float* sig = (const float*)d_in[0];    // (16, 262144) f32
  const float* kern = (const float*)d_in[1];   // (1026, 1024) f32
  float* out = (float*)d_out;                  // (16, 513, 1025, 2) f32

  unsigned short* wsA = (unsigned short*)d_ws;               // 1280*1024 bf16
  unsigned short* wsS = wsA + (size_t)MP2 * NFFT;            // 16*263168 bf16
  // ws use: (1280*1024 + 16*263168)*2 = 11,042,816 bytes

  (void)hipFuncSetAttribute((const void*)stft_mm,
                            hipFuncAttributeMaxDynamicSharedMemorySize, LDS_BYTES);

  prep_A<<<dim3(MP2 * NFFT / 8 / 256), 256, 0, stream>>>(kern, wsA);
  prep_S<<<dim3(NBATCH * SIGP / 8 / 256), 256, 0, stream>>>(sig, wsS);
  stft_mm<<<dim3(4 * 8 * NBATCH), 512, LDS_BYTES, stream>>>(wsA, wsS, out);
  // edge waves: 16*1025 + 16*513 = 24608 = 6152 blocks * 4 waves (exact)
  stft_edge<<<dim3((NBATCH * NT + NBATCH * FB) / 4), 256, 0, stream>>>(wsA, wsS, out);
}